// Round 1
// baseline (1765.763 us; speedup 1.0000x reference)
//
#include <hip/hip_runtime.h>
#include <stdint.h>

#define BB 8
#define NN 8192
#define CC_FEAT 64
#define NPOINT 1024
#define NSAMPLE 32

__device__ __forceinline__ unsigned long long shfl_down_u64(unsigned long long v, int off) {
    unsigned int lo = (unsigned int)(v & 0xffffffffull);
    unsigned int hi = (unsigned int)(v >> 32);
    lo = __shfl_down(lo, off);
    hi = __shfl_down(hi, off);
    return ((unsigned long long)hi << 32) | (unsigned long long)lo;
}

// ---------------------------------------------------------------------------
// Kernel 1: farthest point sampling. One block (1024 threads) per batch.
// Writes new_xyz (exact copies of selected points) into d_out[0 : B*NPOINT*3].
// Exactness: d2 = ((dx*dx + dy*dy) + dz*dz) with _rn intrinsics (no fma
// contraction) to match numpy; argmax ties -> lowest index via ~idx packing.
// ---------------------------------------------------------------------------
__global__ __launch_bounds__(1024) void fps_kernel(const float* __restrict__ xyz,
                                                   float* __restrict__ new_xyz) {
    __shared__ float sx[NN];
    __shared__ float sy[NN];
    __shared__ float sz[NN];
    __shared__ unsigned long long wred[16];
    __shared__ int s_cur;

    const int b = blockIdx.x;
    const int t = threadIdx.x;
    const int lane = t & 63;
    const int wv = t >> 6;
    const float* base = xyz + (size_t)b * NN * 3;

    float px[8], py[8], pz[8], dist[8];
    unsigned int nidx[8];
#pragma unroll
    for (int i = 0; i < 8; ++i) {
        int p = t + (i << 10);
        float x = base[p * 3 + 0];
        float y = base[p * 3 + 1];
        float z = base[p * 3 + 2];
        sx[p] = x; sy[p] = y; sz[p] = z;
        px[i] = x; py[i] = y; pz[i] = z;
        dist[i] = 1e10f;              // f32(10000000000.0) is exact
        nidx[i] = ~(unsigned int)p;   // bigger ~p == smaller p on ties
    }
    __syncthreads();

    float* outb = new_xyz + (size_t)b * NPOINT * 3;
    if (t == 0) { outb[0] = sx[0]; outb[1] = sy[0]; outb[2] = sz[0]; }

    int cur = 0;
    for (int j = 1; j < NPOINT; ++j) {
        float lx = sx[cur], ly = sy[cur], lz = sz[cur];
        unsigned long long best = 0ull;
#pragma unroll
        for (int i = 0; i < 8; ++i) {
            float dx = __fsub_rn(px[i], lx);
            float dy = __fsub_rn(py[i], ly);
            float dz = __fsub_rn(pz[i], lz);
            float d2 = __fadd_rn(__fadd_rn(__fmul_rn(dx, dx), __fmul_rn(dy, dy)),
                                 __fmul_rn(dz, dz));
            float dd = fminf(dist[i], d2);
            dist[i] = dd;
            unsigned long long key =
                ((unsigned long long)__float_as_uint(dd) << 32) |
                (unsigned long long)nidx[i];
            best = (best > key) ? best : key;
        }
#pragma unroll
        for (int off = 32; off > 0; off >>= 1) {
            unsigned long long o = shfl_down_u64(best, off);
            best = (best > o) ? best : o;
        }
        if (lane == 0) wred[wv] = best;
        __syncthreads();
        if (t == 0) {
            unsigned long long bb = wred[0];
#pragma unroll
            for (int w = 1; w < 16; ++w) {
                unsigned long long o = wred[w];
                bb = (bb > o) ? bb : o;
            }
            int idx = (int)(~(unsigned int)(bb & 0xffffffffull));
            s_cur = idx;
            outb[j * 3 + 0] = sx[idx];
            outb[j * 3 + 1] = sy[idx];
            outb[j * 3 + 2] = sz[idx];
        }
        __syncthreads();
        cur = s_cur;
    }
}

// ---------------------------------------------------------------------------
// Kernel 2: ball query. 4 waves/block, one centroid per wave.
// First NSAMPLE in-radius indices in ascending order, padded with first hit.
// ---------------------------------------------------------------------------
__global__ __launch_bounds__(256) void ballq_kernel(const float* __restrict__ xyz,
                                                    const float* __restrict__ new_xyz,
                                                    int* __restrict__ gidx) {
    __shared__ int s_hits[4][NSAMPLE];
    const int t = threadIdx.x;
    const int lane = t & 63;
    const int wv = t >> 6;
    const int g = blockIdx.x * 4 + wv;        // global centroid id
    const int bi = g >> 10;
    const float R2 = (float)(0.4 * 0.4);      // 0.15999999642f, matches ref

    const float cx = new_xyz[g * 3 + 0];
    const float cy = new_xyz[g * 3 + 1];
    const float cz = new_xyz[g * 3 + 2];
    const float* base = xyz + (size_t)bi * NN * 3;

    int have = 0;
    for (int chunk = 0; chunk < (NN / 64) && have < NSAMPLE; ++chunk) {
        int p = (chunk << 6) + lane;
        float dx = __fsub_rn(cx, base[p * 3 + 0]);
        float dy = __fsub_rn(cy, base[p * 3 + 1]);
        float dz = __fsub_rn(cz, base[p * 3 + 2]);
        float d2 = __fadd_rn(__fadd_rn(__fmul_rn(dx, dx), __fmul_rn(dy, dy)),
                             __fmul_rn(dz, dz));
        bool in = d2 < R2;
        unsigned long long m = __ballot(in);
        int pre = __popcll(m & ((1ull << lane) - 1ull));
        int slot = have + pre;
        if (in && slot < NSAMPLE) s_hits[wv][slot] = p;
        have += (int)__popcll(m);
    }
    __syncthreads();
    if (lane < NSAMPLE) {
        int first = s_hits[wv][0];
        int v = (lane < have) ? s_hits[wv][lane] : first;
        gidx[(size_t)g * NSAMPLE + lane] = v;
    }
}

// ---------------------------------------------------------------------------
// Kernel 3: gather + 3-layer MLP (67->64->64->128) + max over k.
// One block (256 threads) per (b,m) group of 32 points. ~50KB LDS.
// Weights staged transposed (wt[c][o]); wt3 overwrites wt1/wt2 after layer2.
// ---------------------------------------------------------------------------
__global__ __launch_bounds__(256) void mlp_kernel(const float* __restrict__ xyz,
                                                  const float* __restrict__ features,
                                                  const float* __restrict__ w1,
                                                  const float* __restrict__ b1,
                                                  const float* __restrict__ w2,
                                                  const float* __restrict__ b2,
                                                  const float* __restrict__ w3,
                                                  const float* __restrict__ b3,
                                                  const float* __restrict__ new_xyz,
                                                  const int* __restrict__ gidx,
                                                  float* __restrict__ out_feat) {
    __shared__ __align__(16) float s_w[8448];  // wt1[68][64] @0, wt2[64][64] @4352; later wt3[64][128] @0
    __shared__ __align__(16) float s_x[2176];  // x[32][68]; later reused as red[4][128]
    __shared__ __align__(16) float s_h[2048];  // h[32][64]
    __shared__ int s_gi[32];

    const int t = threadIdx.x;
    const int g = blockIdx.x;
    const int bi = g >> 10;
    const int mi = g & 1023;

    // ---- Phase 0: indices + stage wt1, wt2 ----
    if (t < 32) s_gi[t] = gidx[g * 32 + t];
    for (int i = t; i < 4288; i += 256) {          // w1 (64,67) -> wt1[c][o]
        int o = i / 67;
        int c = i - o * 67;
        s_w[c * 64 + o] = w1[i];
    }
    if (t < 64) s_w[67 * 64 + t] = 0.0f;           // zero pad row c=67
    for (int i = t; i < 4096; i += 256) {          // w2 (64,64) -> wt2[c][o]
        int o = i >> 6;
        int c = i & 63;
        s_w[4352 + c * 64 + o] = w2[i];
    }
    __syncthreads();

    // ---- Phase 1: gather x = [xyz_rel(3) | feat(64)], pad c=67 ----
    {
        int cc = t & 63, kg = t >> 6;
#pragma unroll
        for (int r = 0; r < 8; ++r) {
            int k = (kg << 3) + r;
            int row = s_gi[k];
            s_x[k * 68 + 3 + cc] = features[(bi * NN + row) * 64 + cc];
        }
    }
    if (t < 96) {
        int k = t / 3, d = t - k * 3;
        int row = s_gi[k];
        s_x[k * 68 + d] = xyz[(bi * NN + row) * 3 + d] - new_xyz[g * 3 + d];
    }
    if (t < 32) s_x[t * 68 + 67] = 0.0f;
    __syncthreads();

    // ---- Layer 1: 67(+1 pad) -> 64 ----
    const int o = t & 31;
    const int pg = t >> 5;
    const int p0 = pg * 4;
    {
        float acc0[4] = {0.f, 0.f, 0.f, 0.f};
        float acc1[4] = {0.f, 0.f, 0.f, 0.f};
        float bo0 = b1[o], bo1 = b1[o + 32];
        for (int cc = 0; cc < 68; cc += 4) {
            float4 xv[4];
#pragma unroll
            for (int i = 0; i < 4; ++i)
                xv[i] = *(const float4*)&s_x[(p0 + i) * 68 + cc];
#pragma unroll
            for (int jj = 0; jj < 4; ++jj) {
                float wa = s_w[(cc + jj) * 64 + o];
                float wb = s_w[(cc + jj) * 64 + o + 32];
#pragma unroll
                for (int i = 0; i < 4; ++i) {
                    float xc = (jj == 0) ? xv[i].x : (jj == 1) ? xv[i].y
                             : (jj == 2) ? xv[i].z : xv[i].w;
                    acc0[i] += xc * wa;
                    acc1[i] += xc * wb;
                }
            }
        }
#pragma unroll
        for (int i = 0; i < 4; ++i) {
            s_h[(p0 + i) * 64 + o]      = fmaxf(acc0[i] + bo0, 0.0f);
            s_h[(p0 + i) * 64 + o + 32] = fmaxf(acc1[i] + bo1, 0.0f);
        }
    }
    __syncthreads();

    // ---- Layer 2: 64 -> 64 (keep results in regs across the barrier) ----
    {
        float acc0[4] = {0.f, 0.f, 0.f, 0.f};
        float acc1[4] = {0.f, 0.f, 0.f, 0.f};
        float bo0 = b2[o], bo1 = b2[o + 32];
        for (int cc = 0; cc < 64; cc += 4) {
            float4 hv[4];
#pragma unroll
            for (int i = 0; i < 4; ++i)
                hv[i] = *(const float4*)&s_h[(p0 + i) * 64 + cc];
#pragma unroll
            for (int jj = 0; jj < 4; ++jj) {
                float wa = s_w[4352 + (cc + jj) * 64 + o];
                float wb = s_w[4352 + (cc + jj) * 64 + o + 32];
#pragma unroll
                for (int i = 0; i < 4; ++i) {
                    float hc = (jj == 0) ? hv[i].x : (jj == 1) ? hv[i].y
                             : (jj == 2) ? hv[i].z : hv[i].w;
                    acc0[i] += hc * wa;
                    acc1[i] += hc * wb;
                }
            }
        }
        __syncthreads();  // everyone done reading h1 and wt2
#pragma unroll
        for (int i = 0; i < 4; ++i) {
            s_h[(p0 + i) * 64 + o]      = fmaxf(acc0[i] + bo0, 0.0f);
            s_h[(p0 + i) * 64 + o + 32] = fmaxf(acc1[i] + bo1, 0.0f);
        }
    }
    // stage wt3 (overwrites wt1/wt2 region) while h2 is being written
    for (int i = t; i < 8192; i += 256) {          // w3 (128,64) -> wt3[c][o]
        int o3 = i >> 6;
        int c3 = i & 63;
        s_w[c3 * 128 + o3] = w3[i];
    }
    __syncthreads();

    // ---- Layer 3: 64 -> 128, fused max over k ----
    {
        const int oo = t & 63;
        const int qg = t >> 6;
        const int q0 = qg * 8;
        float a0[8] = {0,0,0,0,0,0,0,0};
        float a1[8] = {0,0,0,0,0,0,0,0};
        for (int cc = 0; cc < 64; cc += 4) {
            float wa[4], wb[4];
#pragma unroll
            for (int jj = 0; jj < 4; ++jj) {
                wa[jj] = s_w[(cc + jj) * 128 + oo];
                wb[jj] = s_w[(cc + jj) * 128 + oo + 64];
            }
#pragma unroll
            for (int i = 0; i < 8; ++i) {
                float4 hv = *(const float4*)&s_h[(q0 + i) * 64 + cc];
                a0[i] += hv.x * wa[0] + hv.y * wa[1] + hv.z * wa[2] + hv.w * wa[3];
                a1[i] += hv.x * wb[0] + hv.y * wb[1] + hv.z * wb[2] + hv.w * wb[3];
            }
        }
        float m0 = a0[0], m1 = a1[0];
#pragma unroll
        for (int i = 1; i < 8; ++i) {
            m0 = fmaxf(m0, a0[i]);
            m1 = fmaxf(m1, a1[i]);
        }
        // reduce buffer reuses s_x (dead since layer 1)
        s_x[qg * 128 + oo]      = m0;
        s_x[qg * 128 + oo + 64] = m1;
    }
    __syncthreads();
    if (t < 128) {
        float v = fmaxf(fmaxf(s_x[t], s_x[128 + t]),
                        fmaxf(s_x[256 + t], s_x[384 + t]));
        v = fmaxf(v + b3[t], 0.0f);
        out_feat[(size_t)bi * 128 * 1024 + t * 1024 + mi] = v;
    }
}

extern "C" void kernel_launch(void* const* d_in, const int* in_sizes, int n_in,
                              void* d_out, int out_size, void* d_ws, size_t ws_size,
                              hipStream_t stream) {
    const float* xyz      = (const float*)d_in[0];
    const float* features = (const float*)d_in[1];
    const float* w1       = (const float*)d_in[2];
    const float* b1       = (const float*)d_in[3];
    const float* w2       = (const float*)d_in[4];
    const float* b2       = (const float*)d_in[5];
    const float* w3       = (const float*)d_in[6];
    const float* b3       = (const float*)d_in[7];

    float* out      = (float*)d_out;
    float* new_xyz  = out;                         // B*NPOINT*3 = 24576 floats
    float* out_feat = out + BB * NPOINT * 3;       // B*128*NPOINT
    int*   gidx     = (int*)d_ws;                  // B*NPOINT*NSAMPLE ints = 1MB

    fps_kernel<<<BB, 1024, 0, stream>>>(xyz, new_xyz);
    ballq_kernel<<<(BB * NPOINT) / 4, 256, 0, stream>>>(xyz, new_xyz, gidx);
    mlp_kernel<<<BB * NPOINT, 256, 0, stream>>>(xyz, features, w1, b1, w2, b2,
                                                w3, b3, new_xyz, gidx, out_feat);
}

// Round 2
// 1539.672 us; speedup vs baseline: 1.1468x; 1.1468x over previous
//
#include <hip/hip_runtime.h>
#include <stdint.h>

#define BB 8
#define NN 8192
#define NPOINT 1024
#define NSAMPLE 32

__device__ __forceinline__ unsigned long long shfl_down_u64(unsigned long long v, int off) {
    unsigned int lo = (unsigned int)(v & 0xffffffffull);
    unsigned int hi = (unsigned int)(v >> 32);
    lo = __shfl_down(lo, off);
    hi = __shfl_down(hi, off);
    return ((unsigned long long)hi << 32) | (unsigned long long)lo;
}

// ---------------------------------------------------------------------------
// Kernel 1: farthest point sampling. One block (256 threads, 32 pts/thread)
// per batch. Bit-exact vs numpy: d2 = ((dx*dx + dy*dy) + dz*dz) with _rn
// intrinsics (no fma contraction); argmax ties -> lowest index (strict >
// within thread over ascending indices; u64 (bits<<32)|~idx across threads).
// ---------------------------------------------------------------------------
__global__ __launch_bounds__(256) void fps_kernel(const float* __restrict__ xyz,
                                                  float* __restrict__ new_xyz) {
    __shared__ float sx[NN];
    __shared__ float sy[NN];
    __shared__ float sz[NN];
    __shared__ unsigned long long wred[4];
    __shared__ int s_sel[NPOINT];

    const int b = blockIdx.x;
    const int t = threadIdx.x;
    const int lane = t & 63;
    const int wv = t >> 6;
    const float* base = xyz + (size_t)b * NN * 3;

    float px[32], py[32], pz[32], dist[32];
#pragma unroll
    for (int i = 0; i < 32; ++i) {
        int p = t + (i << 8);               // lane-consecutive: coalesced glb,
        float x = base[p * 3 + 0];          // conflict-free LDS (bank = t%32)
        float y = base[p * 3 + 1];
        float z = base[p * 3 + 2];
        sx[p] = x; sy[p] = y; sz[p] = z;
        px[i] = x; py[i] = y; pz[i] = z;
        dist[i] = 1e10f;                    // f32(10000000000.0) exact
    }
    if (t == 0) s_sel[0] = 0;
    __syncthreads();

    int cur = 0;
    for (int j = 1; j < NPOINT; ++j) {
        float lx = sx[cur], ly = sy[cur], lz = sz[cur];   // LDS broadcast
        float bd = -1.0f;
        int bi = 0;
#pragma unroll
        for (int i = 0; i < 32; ++i) {
            float dx = __fsub_rn(px[i], lx);
            float dy = __fsub_rn(py[i], ly);
            float dz = __fsub_rn(pz[i], lz);
            float d2 = __fadd_rn(__fadd_rn(__fmul_rn(dx, dx), __fmul_rn(dy, dy)),
                                 __fmul_rn(dz, dz));
            float dd = fminf(dist[i], d2);
            dist[i] = dd;
            bool gt = dd > bd;              // strict: keeps lowest i on ties
            bd = gt ? dd : bd;
            bi = gt ? i : bi;               // i is an inline constant
        }
        int gi = t + (bi << 8);
        unsigned long long key =
            ((unsigned long long)__float_as_uint(bd) << 32) |
            (unsigned long long)(~(unsigned int)gi);      // bigger ~gi == smaller gi
#pragma unroll
        for (int off = 32; off > 0; off >>= 1) {
            unsigned long long o = shfl_down_u64(key, off);
            key = (key > o) ? key : o;
        }
        if (lane == 0) wred[wv] = key;
        __syncthreads();
        if (t == 0) {
            unsigned long long b0 = wred[0], b1 = wred[1];
            unsigned long long b2 = wred[2], b3 = wred[3];
            b0 = (b0 > b1) ? b0 : b1;
            b2 = (b2 > b3) ? b2 : b3;
            b0 = (b0 > b2) ? b0 : b2;
            s_sel[j] = (int)(~(unsigned int)(b0 & 0xffffffffull));
        }
        __syncthreads();
        cur = s_sel[j];
    }

    float* outb = new_xyz + (size_t)b * NPOINT * 3;
    for (int k = t; k < NPOINT; k += 256) {
        int id = s_sel[k];
        outb[k * 3 + 0] = sx[id];
        outb[k * 3 + 1] = sy[id];
        outb[k * 3 + 2] = sz[id];
    }
}

// ---------------------------------------------------------------------------
// Kernel 2: ball query. 4 waves/block, one centroid per wave.
// First NSAMPLE in-radius indices in ascending order, padded with first hit.
// ---------------------------------------------------------------------------
__global__ __launch_bounds__(256) void ballq_kernel(const float* __restrict__ xyz,
                                                    const float* __restrict__ new_xyz,
                                                    int* __restrict__ gidx) {
    __shared__ int s_hits[4][NSAMPLE];
    const int t = threadIdx.x;
    const int lane = t & 63;
    const int wv = t >> 6;
    const int g = blockIdx.x * 4 + wv;        // global centroid id
    const int bi = g >> 10;
    const float R2 = (float)(0.4 * 0.4);      // 0.15999999642f, matches ref

    const float cx = new_xyz[g * 3 + 0];
    const float cy = new_xyz[g * 3 + 1];
    const float cz = new_xyz[g * 3 + 2];
    const float* base = xyz + (size_t)bi * NN * 3;

    int have = 0;
    for (int chunk = 0; chunk < (NN / 64) && have < NSAMPLE; ++chunk) {
        int p = (chunk << 6) + lane;
        float dx = __fsub_rn(cx, base[p * 3 + 0]);
        float dy = __fsub_rn(cy, base[p * 3 + 1]);
        float dz = __fsub_rn(cz, base[p * 3 + 2]);
        float d2 = __fadd_rn(__fadd_rn(__fmul_rn(dx, dx), __fmul_rn(dy, dy)),
                             __fmul_rn(dz, dz));
        bool in = d2 < R2;
        unsigned long long m = __ballot(in);
        int pre = __popcll(m & ((1ull << lane) - 1ull));
        int slot = have + pre;
        if (in && slot < NSAMPLE) s_hits[wv][slot] = p;
        have += (int)__popcll(m);
    }
    __syncthreads();
    if (lane < NSAMPLE) {
        int first = s_hits[wv][0];
        int v = (lane < have) ? s_hits[wv][lane] : first;
        gidx[(size_t)g * NSAMPLE + lane] = v;
    }
}

// ---------------------------------------------------------------------------
// Kernel 3: gather + 3-layer MLP (67->64->64->128) + max over k.
// One block (256 threads) per (b,m) group of 32 points. ~50KB LDS.
// Weights staged transposed (wt[c][o]); wt3 overwrites wt1/wt2 after layer2.
// ---------------------------------------------------------------------------
__global__ __launch_bounds__(256) void mlp_kernel(const float* __restrict__ xyz,
                                                  const float* __restrict__ features,
                                                  const float* __restrict__ w1,
                                                  const float* __restrict__ b1,
                                                  const float* __restrict__ w2,
                                                  const float* __restrict__ b2,
                                                  const float* __restrict__ w3,
                                                  const float* __restrict__ b3,
                                                  const float* __restrict__ new_xyz,
                                                  const int* __restrict__ gidx,
                                                  float* __restrict__ out_feat) {
    __shared__ __align__(16) float s_w[8448];  // wt1[68][64] @0, wt2[64][64] @4352; later wt3[64][128] @0
    __shared__ __align__(16) float s_x[2176];  // x[32][68]; later reused as red[4][128]
    __shared__ __align__(16) float s_h[2048];  // h[32][64]
    __shared__ int s_gi[32];

    const int t = threadIdx.x;
    const int g = blockIdx.x;
    const int bi = g >> 10;
    const int mi = g & 1023;

    // ---- Phase 0: indices + stage wt1, wt2 ----
    if (t < 32) s_gi[t] = gidx[g * 32 + t];
    for (int i = t; i < 4288; i += 256) {          // w1 (64,67) -> wt1[c][o]
        int o = i / 67;
        int c = i - o * 67;
        s_w[c * 64 + o] = w1[i];
    }
    if (t < 64) s_w[67 * 64 + t] = 0.0f;           // zero pad row c=67
    for (int i = t; i < 4096; i += 256) {          // w2 (64,64) -> wt2[c][o]
        int o = i >> 6;
        int c = i & 63;
        s_w[4352 + c * 64 + o] = w2[i];
    }
    __syncthreads();

    // ---- Phase 1: gather x = [xyz_rel(3) | feat(64)], pad c=67 ----
    {
        int cc = t & 63, kg = t >> 6;
#pragma unroll
        for (int r = 0; r < 8; ++r) {
            int k = (kg << 3) + r;
            int row = s_gi[k];
            s_x[k * 68 + 3 + cc] = features[(bi * NN + row) * 64 + cc];
        }
    }
    if (t < 96) {
        int k = t / 3, d = t - k * 3;
        int row = s_gi[k];
        s_x[k * 68 + d] = xyz[(bi * NN + row) * 3 + d] - new_xyz[g * 3 + d];
    }
    if (t < 32) s_x[t * 68 + 67] = 0.0f;
    __syncthreads();

    // ---- Layer 1: 67(+1 pad) -> 64 ----
    const int o = t & 31;
    const int pg = t >> 5;
    const int p0 = pg * 4;
    {
        float acc0[4] = {0.f, 0.f, 0.f, 0.f};
        float acc1[4] = {0.f, 0.f, 0.f, 0.f};
        float bo0 = b1[o], bo1 = b1[o + 32];
        for (int cc = 0; cc < 68; cc += 4) {
            float4 xv[4];
#pragma unroll
            for (int i = 0; i < 4; ++i)
                xv[i] = *(const float4*)&s_x[(p0 + i) * 68 + cc];
#pragma unroll
            for (int jj = 0; jj < 4; ++jj) {
                float wa = s_w[(cc + jj) * 64 + o];
                float wb = s_w[(cc + jj) * 64 + o + 32];
#pragma unroll
                for (int i = 0; i < 4; ++i) {
                    float xc = (jj == 0) ? xv[i].x : (jj == 1) ? xv[i].y
                             : (jj == 2) ? xv[i].z : xv[i].w;
                    acc0[i] += xc * wa;
                    acc1[i] += xc * wb;
                }
            }
        }
#pragma unroll
        for (int i = 0; i < 4; ++i) {
            s_h[(p0 + i) * 64 + o]      = fmaxf(acc0[i] + bo0, 0.0f);
            s_h[(p0 + i) * 64 + o + 32] = fmaxf(acc1[i] + bo1, 0.0f);
        }
    }
    __syncthreads();

    // ---- Layer 2: 64 -> 64 (keep results in regs across the barrier) ----
    {
        float acc0[4] = {0.f, 0.f, 0.f, 0.f};
        float acc1[4] = {0.f, 0.f, 0.f, 0.f};
        float bo0 = b2[o], bo1 = b2[o + 32];
        for (int cc = 0; cc < 64; cc += 4) {
            float4 hv[4];
#pragma unroll
            for (int i = 0; i < 4; ++i)
                hv[i] = *(const float4*)&s_h[(p0 + i) * 64 + cc];
#pragma unroll
            for (int jj = 0; jj < 4; ++jj) {
                float wa = s_w[4352 + (cc + jj) * 64 + o];
                float wb = s_w[4352 + (cc + jj) * 64 + o + 32];
#pragma unroll
                for (int i = 0; i < 4; ++i) {
                    float hc = (jj == 0) ? hv[i].x : (jj == 1) ? hv[i].y
                             : (jj == 2) ? hv[i].z : hv[i].w;
                    acc0[i] += hc * wa;
                    acc1[i] += hc * wb;
                }
            }
        }
        __syncthreads();  // everyone done reading h1 and wt2
#pragma unroll
        for (int i = 0; i < 4; ++i) {
            s_h[(p0 + i) * 64 + o]      = fmaxf(acc0[i] + bo0, 0.0f);
            s_h[(p0 + i) * 64 + o + 32] = fmaxf(acc1[i] + bo1, 0.0f);
        }
    }
    // stage wt3 (overwrites wt1/wt2 region) while h2 is being written
    for (int i = t; i < 8192; i += 256) {          // w3 (128,64) -> wt3[c][o]
        int o3 = i >> 6;
        int c3 = i & 63;
        s_w[c3 * 128 + o3] = w3[i];
    }
    __syncthreads();

    // ---- Layer 3: 64 -> 128, fused max over k ----
    {
        const int oo = t & 63;
        const int qg = t >> 6;
        const int q0 = qg * 8;
        float a0[8] = {0,0,0,0,0,0,0,0};
        float a1[8] = {0,0,0,0,0,0,0,0};
        for (int cc = 0; cc < 64; cc += 4) {
            float wa[4], wb[4];
#pragma unroll
            for (int jj = 0; jj < 4; ++jj) {
                wa[jj] = s_w[(cc + jj) * 128 + oo];
                wb[jj] = s_w[(cc + jj) * 128 + oo + 64];
            }
#pragma unroll
            for (int i = 0; i < 8; ++i) {
                float4 hv = *(const float4*)&s_h[(q0 + i) * 64 + cc];
                a0[i] += hv.x * wa[0] + hv.y * wa[1] + hv.z * wa[2] + hv.w * wa[3];
                a1[i] += hv.x * wb[0] + hv.y * wb[1] + hv.z * wb[2] + hv.w * wb[3];
            }
        }
        float m0 = a0[0], m1 = a1[0];
#pragma unroll
        for (int i = 1; i < 8; ++i) {
            m0 = fmaxf(m0, a0[i]);
            m1 = fmaxf(m1, a1[i]);
        }
        // reduce buffer reuses s_x (dead since layer 1)
        s_x[qg * 128 + oo]      = m0;
        s_x[qg * 128 + oo + 64] = m1;
    }
    __syncthreads();
    if (t < 128) {
        float v = fmaxf(fmaxf(s_x[t], s_x[128 + t]),
                        fmaxf(s_x[256 + t], s_x[384 + t]));
        v = fmaxf(v + b3[t], 0.0f);
        out_feat[(size_t)bi * 128 * 1024 + t * 1024 + mi] = v;
    }
}

extern "C" void kernel_launch(void* const* d_in, const int* in_sizes, int n_in,
                              void* d_out, int out_size, void* d_ws, size_t ws_size,
                              hipStream_t stream) {
    const float* xyz      = (const float*)d_in[0];
    const float* features = (const float*)d_in[1];
    const float* w1       = (const float*)d_in[2];
    const float* b1       = (const float*)d_in[3];
    const float* w2       = (const float*)d_in[4];
    const float* b2       = (const float*)d_in[5];
    const float* w3       = (const float*)d_in[6];
    const float* b3       = (const float*)d_in[7];

    float* out      = (float*)d_out;
    float* new_xyz  = out;                         // B*NPOINT*3 = 24576 floats
    float* out_feat = out + BB * NPOINT * 3;       // B*128*NPOINT
    int*   gidx     = (int*)d_ws;                  // B*NPOINT*NSAMPLE ints = 1MB

    fps_kernel<<<BB, 256, 0, stream>>>(xyz, new_xyz);
    ballq_kernel<<<(BB * NPOINT) / 4, 256, 0, stream>>>(xyz, new_xyz, gidx);
    mlp_kernel<<<BB * NPOINT, 256, 0, stream>>>(xyz, features, w1, b1, w2, b2,
                                                w3, b3, new_xyz, gidx, out_feat);
}

// Round 3
// 1347.335 us; speedup vs baseline: 1.3106x; 1.1428x over previous
//
#include <hip/hip_runtime.h>
#include <stdint.h>

#define BB 8
#define NN 8192
#define NPOINT 1024
#define NSAMPLE 32

__device__ __forceinline__ unsigned long long u64max(unsigned long long a,
                                                     unsigned long long b) {
    return (a > b) ? a : b;
}

// One DPP max step on a u64 key. Invalid/masked-off lanes contribute 0
// (identity for unsigned max): old=0, bound_ctrl=true.
template <int CTRL, int RMASK>
__device__ __forceinline__ unsigned long long dpp_max_step(unsigned long long key) {
    int lo = (int)(unsigned int)(key & 0xffffffffull);
    int hi = (int)(unsigned int)(key >> 32);
    int tlo = __builtin_amdgcn_update_dpp(0, lo, CTRL, RMASK, 0xF, true);
    int thi = __builtin_amdgcn_update_dpp(0, hi, CTRL, RMASK, 0xF, true);
    unsigned long long t = ((unsigned long long)(unsigned int)thi << 32) |
                           (unsigned long long)(unsigned int)tlo;
    return u64max(key, t);
}

// Full wave64 max-reduce; result valid in lane 63.
__device__ __forceinline__ unsigned long long dpp_wave_max(unsigned long long key) {
    key = dpp_max_step<0x111, 0xF>(key);  // row_shr:1
    key = dpp_max_step<0x112, 0xF>(key);  // row_shr:2
    key = dpp_max_step<0x114, 0xF>(key);  // row_shr:4
    key = dpp_max_step<0x118, 0xF>(key);  // row_shr:8
    key = dpp_max_step<0x142, 0xA>(key);  // row_bcast:15 -> rows 1,3
    key = dpp_max_step<0x143, 0xC>(key);  // row_bcast:31 -> rows 2,3
    return key;
}

// ---------------------------------------------------------------------------
// Kernel 1: farthest point sampling. One block (256 threads, 32 pts/thread)
// per batch. Bit-exact vs numpy: d2 = ((dx*dx + dy*dy) + dz*dz) with _rn
// intrinsics (no fma contraction); argmax ties -> lowest index (strict >
// within thread over ascending indices; u64 (bits<<32)|~idx across threads).
// Tail: DPP wave reduce (lane 63 writes partial), ONE barrier, then all
// threads redundantly fold the 4 partials (broadcast LDS reads). wred is
// double-buffered on j&1 so one barrier per iteration is race-free.
// ---------------------------------------------------------------------------
__global__ __launch_bounds__(256) void fps_kernel(const float* __restrict__ xyz,
                                                  float* __restrict__ new_xyz) {
    __shared__ float sx[NN];
    __shared__ float sy[NN];
    __shared__ float sz[NN];
    __shared__ __align__(16) unsigned long long wred[2][4];
    __shared__ int s_sel[NPOINT];

    const int b = blockIdx.x;
    const int t = threadIdx.x;
    const int lane = t & 63;
    const int wv = t >> 6;
    const float* base = xyz + (size_t)b * NN * 3;

    float px[32], py[32], pz[32], dist[32];
#pragma unroll
    for (int i = 0; i < 32; ++i) {
        int p = t + (i << 8);               // lane-consecutive: coalesced glb,
        float x = base[p * 3 + 0];          // conflict-free LDS (bank = t%32)
        float y = base[p * 3 + 1];
        float z = base[p * 3 + 2];
        sx[p] = x; sy[p] = y; sz[p] = z;
        px[i] = x; py[i] = y; pz[i] = z;
        dist[i] = 1e10f;                    // f32(10000000000.0) exact
    }
    if (t == 0) s_sel[0] = 0;
    __syncthreads();

    int cur = 0;
    for (int j = 1; j < NPOINT; ++j) {
        float lx = sx[cur], ly = sy[cur], lz = sz[cur];   // LDS broadcast
        float bd = -1.0f;
        int bi = 0;
#pragma unroll
        for (int i = 0; i < 32; ++i) {
            float dx = __fsub_rn(px[i], lx);
            float dy = __fsub_rn(py[i], ly);
            float dz = __fsub_rn(pz[i], lz);
            float d2 = __fadd_rn(__fadd_rn(__fmul_rn(dx, dx), __fmul_rn(dy, dy)),
                                 __fmul_rn(dz, dz));
            float dd = fminf(dist[i], d2);
            dist[i] = dd;
            bool gt = dd > bd;              // strict: keeps lowest i on ties
            bd = gt ? dd : bd;
            bi = gt ? i : bi;               // i is an inline constant
        }
        int gi = t + (bi << 8);
        unsigned long long key =
            ((unsigned long long)__float_as_uint(bd) << 32) |
            (unsigned long long)(~(unsigned int)gi);      // bigger ~gi == smaller gi
        key = dpp_wave_max(key);
        if (lane == 63) wred[j & 1][wv] = key;
        __syncthreads();
        {
            const unsigned long long* wr = wred[j & 1];
            ulonglong2 p01 = *(const ulonglong2*)&wr[0];  // broadcast b128
            ulonglong2 p23 = *(const ulonglong2*)&wr[2];
            unsigned long long m = u64max(u64max(p01.x, p01.y),
                                          u64max(p23.x, p23.y));
            cur = (int)(~(unsigned int)(m & 0xffffffffull));
        }
        if (t == 0) s_sel[j] = cur;
    }
    __syncthreads();

    float* outb = new_xyz + (size_t)b * NPOINT * 3;
    for (int k = t; k < NPOINT; k += 256) {
        int id = s_sel[k];
        outb[k * 3 + 0] = sx[id];
        outb[k * 3 + 1] = sy[id];
        outb[k * 3 + 2] = sz[id];
    }
}

// ---------------------------------------------------------------------------
// Kernel 2: ball query. 4 waves/block, one centroid per wave.
// First NSAMPLE in-radius indices in ascending order, padded with first hit.
// ---------------------------------------------------------------------------
__global__ __launch_bounds__(256) void ballq_kernel(const float* __restrict__ xyz,
                                                    const float* __restrict__ new_xyz,
                                                    int* __restrict__ gidx) {
    __shared__ int s_hits[4][NSAMPLE];
    const int t = threadIdx.x;
    const int lane = t & 63;
    const int wv = t >> 6;
    const int g = blockIdx.x * 4 + wv;        // global centroid id
    const int bi = g >> 10;
    const float R2 = (float)(0.4 * 0.4);      // 0.15999999642f, matches ref

    const float cx = new_xyz[g * 3 + 0];
    const float cy = new_xyz[g * 3 + 1];
    const float cz = new_xyz[g * 3 + 2];
    const float* base = xyz + (size_t)bi * NN * 3;

    int have = 0;
    for (int chunk = 0; chunk < (NN / 64) && have < NSAMPLE; ++chunk) {
        int p = (chunk << 6) + lane;
        float dx = __fsub_rn(cx, base[p * 3 + 0]);
        float dy = __fsub_rn(cy, base[p * 3 + 1]);
        float dz = __fsub_rn(cz, base[p * 3 + 2]);
        float d2 = __fadd_rn(__fadd_rn(__fmul_rn(dx, dx), __fmul_rn(dy, dy)),
                             __fmul_rn(dz, dz));
        bool in = d2 < R2;
        unsigned long long m = __ballot(in);
        int pre = __popcll(m & ((1ull << lane) - 1ull));
        int slot = have + pre;
        if (in && slot < NSAMPLE) s_hits[wv][slot] = p;
        have += (int)__popcll(m);
    }
    __syncthreads();
    if (lane < NSAMPLE) {
        int first = s_hits[wv][0];
        int v = (lane < have) ? s_hits[wv][lane] : first;
        gidx[(size_t)g * NSAMPLE + lane] = v;
    }
}

// ---------------------------------------------------------------------------
// Kernel 3: gather + 3-layer MLP (67->64->64->128) + max over k.
// One block (256 threads) per (b,m) group of 32 points. ~50KB LDS.
// Weights staged transposed (wt[c][o]); wt3 overwrites wt1/wt2 after layer2.
// ---------------------------------------------------------------------------
__global__ __launch_bounds__(256) void mlp_kernel(const float* __restrict__ xyz,
                                                  const float* __restrict__ features,
                                                  const float* __restrict__ w1,
                                                  const float* __restrict__ b1,
                                                  const float* __restrict__ w2,
                                                  const float* __restrict__ b2,
                                                  const float* __restrict__ w3,
                                                  const float* __restrict__ b3,
                                                  const float* __restrict__ new_xyz,
                                                  const int* __restrict__ gidx,
                                                  float* __restrict__ out_feat) {
    __shared__ __align__(16) float s_w[8448];  // wt1[68][64] @0, wt2[64][64] @4352; later wt3[64][128] @0
    __shared__ __align__(16) float s_x[2176];  // x[32][68]; later reused as red[4][128]
    __shared__ __align__(16) float s_h[2048];  // h[32][64]
    __shared__ int s_gi[32];

    const int t = threadIdx.x;
    const int g = blockIdx.x;
    const int bi = g >> 10;
    const int mi = g & 1023;

    // ---- Phase 0: indices + stage wt1, wt2 ----
    if (t < 32) s_gi[t] = gidx[g * 32 + t];
    for (int i = t; i < 4288; i += 256) {          // w1 (64,67) -> wt1[c][o]
        int o = i / 67;
        int c = i - o * 67;
        s_w[c * 64 + o] = w1[i];
    }
    if (t < 64) s_w[67 * 64 + t] = 0.0f;           // zero pad row c=67
    for (int i = t; i < 4096; i += 256) {          // w2 (64,64) -> wt2[c][o]
        int o = i >> 6;
        int c = i & 63;
        s_w[4352 + c * 64 + o] = w2[i];
    }
    __syncthreads();

    // ---- Phase 1: gather x = [xyz_rel(3) | feat(64)], pad c=67 ----
    {
        int cc = t & 63, kg = t >> 6;
#pragma unroll
        for (int r = 0; r < 8; ++r) {
            int k = (kg << 3) + r;
            int row = s_gi[k];
            s_x[k * 68 + 3 + cc] = features[(bi * NN + row) * 64 + cc];
        }
    }
    if (t < 96) {
        int k = t / 3, d = t - k * 3;
        int row = s_gi[k];
        s_x[k * 68 + d] = xyz[(bi * NN + row) * 3 + d] - new_xyz[g * 3 + d];
    }
    if (t < 32) s_x[t * 68 + 67] = 0.0f;
    __syncthreads();

    // ---- Layer 1: 67(+1 pad) -> 64 ----
    const int o = t & 31;
    const int pg = t >> 5;
    const int p0 = pg * 4;
    {
        float acc0[4] = {0.f, 0.f, 0.f, 0.f};
        float acc1[4] = {0.f, 0.f, 0.f, 0.f};
        float bo0 = b1[o], bo1 = b1[o + 32];
        for (int cc = 0; cc < 68; cc += 4) {
            float4 xv[4];
#pragma unroll
            for (int i = 0; i < 4; ++i)
                xv[i] = *(const float4*)&s_x[(p0 + i) * 68 + cc];
#pragma unroll
            for (int jj = 0; jj < 4; ++jj) {
                float wa = s_w[(cc + jj) * 64 + o];
                float wb = s_w[(cc + jj) * 64 + o + 32];
#pragma unroll
                for (int i = 0; i < 4; ++i) {
                    float xc = (jj == 0) ? xv[i].x : (jj == 1) ? xv[i].y
                             : (jj == 2) ? xv[i].z : xv[i].w;
                    acc0[i] += xc * wa;
                    acc1[i] += xc * wb;
                }
            }
        }
#pragma unroll
        for (int i = 0; i < 4; ++i) {
            s_h[(p0 + i) * 64 + o]      = fmaxf(acc0[i] + bo0, 0.0f);
            s_h[(p0 + i) * 64 + o + 32] = fmaxf(acc1[i] + bo1, 0.0f);
        }
    }
    __syncthreads();

    // ---- Layer 2: 64 -> 64 (keep results in regs across the barrier) ----
    {
        float acc0[4] = {0.f, 0.f, 0.f, 0.f};
        float acc1[4] = {0.f, 0.f, 0.f, 0.f};
        float bo0 = b2[o], bo1 = b2[o + 32];
        for (int cc = 0; cc < 64; cc += 4) {
            float4 hv[4];
#pragma unroll
            for (int i = 0; i < 4; ++i)
                hv[i] = *(const float4*)&s_h[(p0 + i) * 64 + cc];
#pragma unroll
            for (int jj = 0; jj < 4; ++jj) {
                float wa = s_w[4352 + (cc + jj) * 64 + o];
                float wb = s_w[4352 + (cc + jj) * 64 + o + 32];
#pragma unroll
                for (int i = 0; i < 4; ++i) {
                    float hc = (jj == 0) ? hv[i].x : (jj == 1) ? hv[i].y
                             : (jj == 2) ? hv[i].z : hv[i].w;
                    acc0[i] += hc * wa;
                    acc1[i] += hc * wb;
                }
            }
        }
        __syncthreads();  // everyone done reading h1 and wt2
#pragma unroll
        for (int i = 0; i < 4; ++i) {
            s_h[(p0 + i) * 64 + o]      = fmaxf(acc0[i] + bo0, 0.0f);
            s_h[(p0 + i) * 64 + o + 32] = fmaxf(acc1[i] + bo1, 0.0f);
        }
    }
    // stage wt3 (overwrites wt1/wt2 region) while h2 is being written
    for (int i = t; i < 8192; i += 256) {          // w3 (128,64) -> wt3[c][o]
        int o3 = i >> 6;
        int c3 = i & 63;
        s_w[c3 * 128 + o3] = w3[i];
    }
    __syncthreads();

    // ---- Layer 3: 64 -> 128, fused max over k ----
    {
        const int oo = t & 63;
        const int qg = t >> 6;
        const int q0 = qg * 8;
        float a0[8] = {0,0,0,0,0,0,0,0};
        float a1[8] = {0,0,0,0,0,0,0,0};
        for (int cc = 0; cc < 64; cc += 4) {
            float wa[4], wb[4];
#pragma unroll
            for (int jj = 0; jj < 4; ++jj) {
                wa[jj] = s_w[(cc + jj) * 128 + oo];
                wb[jj] = s_w[(cc + jj) * 128 + oo + 64];
            }
#pragma unroll
            for (int i = 0; i < 8; ++i) {
                float4 hv = *(const float4*)&s_h[(q0 + i) * 64 + cc];
                a0[i] += hv.x * wa[0] + hv.y * wa[1] + hv.z * wa[2] + hv.w * wa[3];
                a1[i] += hv.x * wb[0] + hv.y * wb[1] + hv.z * wb[2] + hv.w * wb[3];
            }
        }
        float m0 = a0[0], m1 = a1[0];
#pragma unroll
        for (int i = 1; i < 8; ++i) {
            m0 = fmaxf(m0, a0[i]);
            m1 = fmaxf(m1, a1[i]);
        }
        // reduce buffer reuses s_x (dead since layer 1)
        s_x[qg * 128 + oo]      = m0;
        s_x[qg * 128 + oo + 64] = m1;
    }
    __syncthreads();
    if (t < 128) {
        float v = fmaxf(fmaxf(s_x[t], s_x[128 + t]),
                        fmaxf(s_x[256 + t], s_x[384 + t]));
        v = fmaxf(v + b3[t], 0.0f);
        out_feat[(size_t)bi * 128 * 1024 + t * 1024 + mi] = v;
    }
}

extern "C" void kernel_launch(void* const* d_in, const int* in_sizes, int n_in,
                              void* d_out, int out_size, void* d_ws, size_t ws_size,
                              hipStream_t stream) {
    const float* xyz      = (const float*)d_in[0];
    const float* features = (const float*)d_in[1];
    const float* w1       = (const float*)d_in[2];
    const float* b1       = (const float*)d_in[3];
    const float* w2       = (const float*)d_in[4];
    const float* b2       = (const float*)d_in[5];
    const float* w3       = (const float*)d_in[6];
    const float* b3       = (const float*)d_in[7];

    float* out      = (float*)d_out;
    float* new_xyz  = out;                         // B*NPOINT*3 = 24576 floats
    float* out_feat = out + BB * NPOINT * 3;       // B*128*NPOINT
    int*   gidx     = (int*)d_ws;                  // B*NPOINT*NSAMPLE ints = 1MB

    fps_kernel<<<BB, 256, 0, stream>>>(xyz, new_xyz);
    ballq_kernel<<<(BB * NPOINT) / 4, 256, 0, stream>>>(xyz, new_xyz, gidx);
    mlp_kernel<<<BB * NPOINT, 256, 0, stream>>>(xyz, features, w1, b1, w2, b2,
                                                w3, b3, new_xyz, gidx, out_feat);
}